// Round 16
// baseline (140.251 us; speedup 1.0000x reference)
//
#include <hip/hip_runtime.h>

#define NUM_HEADS 8
#define DIM 64
#define NCLUST 512
#define NTOK 16384          // 8*2048 tokens
#define ROWLEN 512          // NUM_HEADS*DIM floats per token row
#define NIDS (NTOK * NUM_HEADS)           // 131072
#define NMEANS (NUM_HEADS * NCLUST * DIM) // 262144
#define NCK (NUM_HEADS * NCLUST)          // 4096
#define CAP 8               // candidate slots per token
#define DELTA 0.35f         // ~19 sigma of bf16 coarse-score noise

typedef unsigned long long u64;
typedef short bf16x8 __attribute__((ext_vector_type(8)));
typedef float f32x4 __attribute__((ext_vector_type(4)));

__device__ __forceinline__ unsigned short f2bf(float f) {   // RNE f32->bf16 bits
    unsigned b = __float_as_uint(f);
    return (unsigned short)((b + 0x7fffu + ((b >> 16) & 1u)) >> 16);
}
__device__ __forceinline__ unsigned pack2bf(float lo, float hi) {
    return (unsigned)f2bf(lo) | ((unsigned)f2bf(hi) << 16);
}
__device__ __forceinline__ float bf2f(unsigned short b) {
    return __uint_as_float((unsigned)b << 16);
}
__device__ __forceinline__ u64 packkey(float s, int k) {    // u64 MIN == max s, tie -> min k
    unsigned u = __float_as_uint(s);
    unsigned ord = (u & 0x80000000u) ? ~u : (u | 0x80000000u);
    return ((u64)(~ord) << 32) | (unsigned)k;
}
// swizzled byte offset into a [rows][128B] LDS tile (G4 XOR pattern)
__device__ __forceinline__ int swz(int row, int byte_in_row) {
    return row * 128 + (byte_in_row ^ ((row & 7) << 4));
}

// ---------------- kernel 0: fused prep: q = 0.5*|m|^2 and means f32->bf16 ----
__global__ void vq_prep(const float* __restrict__ means,
                        float* __restrict__ q,
                        unsigned short* __restrict__ mbf) {
    int g = blockIdx.x * blockDim.x + threadIdx.x;   // 0..65535
    int row = g >> 4, c = g & 15;
    float4 v = *(const float4*)(means + (size_t)row * DIM + c * 4);
    ushort4 b;
    b.x = f2bf(v.x); b.y = f2bf(v.y); b.z = f2bf(v.z); b.w = f2bf(v.w);
    *(ushort4*)(mbf + (size_t)row * DIM + c * 4) = b;
    float s = fmaf(v.x, v.x, fmaf(v.y, v.y, fmaf(v.z, v.z, v.w * v.w)));
#pragma unroll
    for (int off = 1; off < 16; off <<= 1) s += __shfl_xor(s, off, 64);
    if (c == 0) q[row] = 0.5f * s;
}

// ---------------- kernel 1: PERSISTENT-MEANS coarse MFMA + candidates + rescore ----
// 512 blocks (2/CU), block = one head (64 blocks/head). The head's FULL bf16
// means table (512 rows x 128B = 64KB) is staged ONCE via global_load_lds
// (linear dest + inverse-swizzled source, r12-validated), then ONE barrier.
// Each wave independently processes 4 token-tiles (2 passes x 2 tiles; b0/b1
// ds_read shared by both tiles) with NO further barriers: candidate lists are
// wave-private LDS slices (same-wave DS ordering). Two-sweep final threshold
// (n~1.05) + CAP overflow exact-fallback (r15-validated).
__global__ __launch_bounds__(256, 2) void vq_score(const float* __restrict__ x,
                                                   const float* __restrict__ means,
                                                   const unsigned short* __restrict__ mbf,
                                                   const float* __restrict__ q,
                                                   float* __restrict__ ids_f) {
    __shared__ __align__(16) unsigned char msq[NCLUST * 128];  // 64 KB all means (swz)
    __shared__ float qs[NCLUST];                               // 2 KB
    __shared__ int cnt[4][32];                                 // wave-private
    __shared__ unsigned short candL[4][32][CAP];               // wave-private

    const int head = blockIdx.x >> 6;        // 64 blocks per head
    const int bloc = blockIdx.x & 63;
    const int tid  = threadIdx.x;
    const int wv = tid >> 6, l = tid & 63;
    const int lg = l >> 4, lc = l & 15;
    const int wg = bloc * 4 + wv;            // 0..255 wave index within head
    const int tile0 = wg * 4;                // this wave's 4 tiles (of 1024)

    // ---- stage ALL 512 means rows (64KB) once; pre-swizzled source ----
    {
        const unsigned char* gbase = (const unsigned char*)mbf
            + (size_t)head * NCLUST * (DIM * 2);
        const int rloc = l >> 3;
        const int srcb = ((l & 7) << 4) ^ (rloc << 4);
#pragma unroll
        for (int i = 0; i < 16; ++i) {
            int chunk = wv * 16 + i;                           // 0..63
            const unsigned char* src = gbase + (chunk * 8 + rloc) * 128 + srcb;
            __builtin_amdgcn_global_load_lds(
                (const __attribute__((address_space(1))) unsigned int*)src,
                (__attribute__((address_space(3))) unsigned int*)(msq + chunk * 1024),
                16, 0, 0);
        }
    }
    qs[tid] = q[head * NCLUST + tid];
    qs[tid + 256] = q[head * NCLUST + tid + 256];

    // ---- A fragments for all 4 tiles upfront (layout validated r5/r12) ----
    bf16x8 af[4][2];
#pragma unroll
    for (int t = 0; t < 4; ++t) {
        const float* xrow = x + (size_t)((tile0 + t) * 16 + lc) * ROWLEN + head * DIM;
#pragma unroll
        for (int ks = 0; ks < 2; ++ks) {
            float av[8];
            *(float4*)&av[0] = *(const float4*)(xrow + ks * 32 + lg * 8);
            *(float4*)&av[4] = *(const float4*)(xrow + ks * 32 + lg * 8 + 4);
#pragma unroll
            for (int j = 0; j < 8; ++j) af[t][ks][j] = (short)f2bf(av[j]);
        }
    }
    __syncthreads();        // the ONLY barrier: msq + qs ready

    // ================= 2 passes x 2 tiles, barrier-free =================
    for (int ps = 0; ps < 2; ++ps) {
        const int ta = ps * 2;                // af index of first tile this pass
        if (l < 32) cnt[wv][l] = 0;           // wave-private reset

        float best[2][4];
#pragma unroll
        for (int tt = 0; tt < 2; ++tt)
#pragma unroll
            for (int r = 0; r < 4; ++r) best[tt][r] = -3.0e38f;

        // ---- sweep 1: fold max (b0/b1 shared across the 2 tiles) ----
        for (int ct = 0; ct < 32; ++ct) {
            bf16x8 b0 = *(const bf16x8*)(msq + swz(ct * 16 + lc, 0 + lg * 16));
            bf16x8 b1 = *(const bf16x8*)(msq + swz(ct * 16 + lc, 64 + lg * 16));
            float qv = qs[ct * 16 + lc];
#pragma unroll
            for (int tt = 0; tt < 2; ++tt) {
                f32x4 acc = (f32x4){-qv, -qv, -qv, -qv};   // C-in = -q_k
                acc = __builtin_amdgcn_mfma_f32_16x16x32_bf16(af[ta + tt][0], b0, acc, 0, 0, 0);
                acc = __builtin_amdgcn_mfma_f32_16x16x32_bf16(af[ta + tt][1], b1, acc, 0, 0, 0);
#pragma unroll
                for (int r = 0; r < 4; ++r) best[tt][r] = fmaxf(best[tt][r], acc[r]);
            }
        }
        float thr[2][4];
#pragma unroll
        for (int tt = 0; tt < 2; ++tt)
#pragma unroll
            for (int r = 0; r < 4; ++r) {
#pragma unroll
                for (int off = 1; off < 16; off <<= 1)
                    best[tt][r] = fmaxf(best[tt][r], __shfl_xor(best[tt][r], off, 64));
                thr[tt][r] = best[tt][r] - DELTA;
            }

        // ---- sweep 2: recompute + insert (final threshold -> n ~ 1.05) ----
        for (int ct = 0; ct < 32; ++ct) {
            bf16x8 b0 = *(const bf16x8*)(msq + swz(ct * 16 + lc, 0 + lg * 16));
            bf16x8 b1 = *(const bf16x8*)(msq + swz(ct * 16 + lc, 64 + lg * 16));
            float qv = qs[ct * 16 + lc];
            int k = ct * 16 + lc;
#pragma unroll
            for (int tt = 0; tt < 2; ++tt) {
                f32x4 acc = (f32x4){-qv, -qv, -qv, -qv};
                acc = __builtin_amdgcn_mfma_f32_16x16x32_bf16(af[ta + tt][0], b0, acc, 0, 0, 0);
                acc = __builtin_amdgcn_mfma_f32_16x16x32_bf16(af[ta + tt][1], b1, acc, 0, 0, 0);
#pragma unroll
                for (int r = 0; r < 4; ++r) {
                    if (acc[r] >= thr[tt][r]) {
                        int tl = tt * 16 + lg * 4 + r;          // 0..31
                        int slot = atomicAdd(&cnt[wv][tl], 1);
                        if (slot < CAP) candL[wv][tl][slot] = (unsigned short)k;
                    }
                }
            }
        }

        // ---- exact f32 rescore (16-lane group per token) + id write ----
        for (int g = 0; g < 8; ++g) {
            int tl = g * 4 + lg;                                // 0..31
            int token = (tile0 + ps * 2 + (tl >> 4)) * 16 + (tl & 15);
            int n = cnt[wv][tl];
            const float4 xv = *(const float4*)(x + (size_t)token * ROWLEN + head * DIM + lc * 4);
            u64 bk = ~0ull;
            if (n > CAP) {      // dropped inserts -> exact full scan (never hot)
                for (int k = 0; k < NCLUST; ++k) {
                    const float4 mv = *(const float4*)(means + ((size_t)head * NCLUST + k) * DIM + lc * 4);
                    float p = fmaf(xv.x, mv.x, fmaf(xv.y, mv.y, fmaf(xv.z, mv.z, xv.w * mv.w)));
#pragma unroll
                    for (int off = 1; off < 16; off <<= 1) p += __shfl_xor(p, off, 64);
                    u64 cd = packkey(p - qs[k], k);
                    bk = cd < bk ? cd : bk;
                }
            } else {
                for (int j = 0; j < n; ++j) {
                    int k = candL[wv][tl][j];
                    const float4 mv = *(const float4*)(means + ((size_t)head * NCLUST + k) * DIM + lc * 4);
                    float p = fmaf(xv.x, mv.x, fmaf(xv.y, mv.y, fmaf(xv.z, mv.z, xv.w * mv.w)));
#pragma unroll
                    for (int off = 1; off < 16; off <<= 1) p += __shfl_xor(p, off, 64);
                    u64 cd = packkey(p - qs[k], k);
                    bk = cd < bk ? cd : bk;
                }
            }
            if (lc == 0) ids_f[(size_t)token * NUM_HEADS + head] = (float)(unsigned)(bk & 0x1ffu);
        }
    }
}

// ---------------- kernel 2: scatter via packed bf16 atomics (r9-validated) ----
__global__ void vq_scatter(const float* __restrict__ x,
                           const float* __restrict__ ids_f,
                           float* __restrict__ counts,
                           unsigned short* __restrict__ sums_bf,
                           int rep_mask) {
    int g = blockIdx.x * blockDim.x + threadIdx.x;
    int p = g >> 5;                      // pair index, 0..131071
    int l32 = threadIdx.x & 31;
    int token = p >> 3;
    int h = p & 7;
    int rep = token & rep_mask;
    int id = (int)ids_f[p];              // broadcast load
    float2 xv = *(const float2*)(x + (size_t)token * ROWLEN + h * DIM + l32 * 2);
    unsigned val = pack2bf(xv.x, xv.y);
    unsigned short* dst = sums_bf + (size_t)rep * NMEANS
                        + (((size_t)h * NCLUST + id) << 6) + l32 * 2;
    asm volatile("global_atomic_pk_add_bf16 %0, %1, off" :: "v"(dst), "v"(val) : "memory");
    if (l32 == 0) atomicAdd(&counts[rep * NCK + h * NCLUST + id], 1.0f);
}

// ---------------- kernel 3: EMA finalize (sums replicas, bf16) ----------------
__global__ void vq_final(const float* __restrict__ means,
                         const float* __restrict__ counts,
                         const unsigned short* __restrict__ sums_bf,
                         float* __restrict__ out_means,
                         int nrep) {
    int i = blockIdx.x * blockDim.x + threadIdx.x;   // 0..262143
    int ck = i >> 6;
    float c = 0.f, s = 0.f;
    for (int r = 0; r < nrep; ++r) {
        c += counts[r * NCK + ck];
        s += bf2f(sums_bf[(size_t)r * NMEANS + i]);
    }
    float nm = s / (1e-6f + c);
    out_means[i] = 0.999f * means[i] + 0.001f * nm;
}

extern "C" void kernel_launch(void* const* d_in, const int* in_sizes, int n_in,
                              void* d_out, int out_size, void* d_ws, size_t ws_size,
                              hipStream_t stream) {
    const float* x     = (const float*)d_in[0];   // [8,2048,512]
    const float* means = (const float*)d_in[1];   // [8,512,64]

    float* out       = (float*)d_out;
    float* ids_f     = out;            // 131072 floats (cluster ids as float)
    float* out_means = out + NIDS;     // 262144 floats

    // ---- workspace layout ----
    float*          q   = (float*)d_ws;                 // NCK f32 (16 KB)
    unsigned short* mbf = (unsigned short*)(q + NCK);   // NMEANS u16 (512 KB)
    float*          fbase = (float*)(mbf + NMEANS);
    size_t core = (size_t)((char*)fbase - (char*)d_ws);

    size_t per_rep = (size_t)NCK * sizeof(float) + (size_t)NMEANS * sizeof(unsigned short);
    int nrep = 1;
    for (int r = 8; r > 1; r >>= 1) {
        if (ws_size >= core + (size_t)r * per_rep) { nrep = r; break; }
    }
    float*          counts  = fbase;                                   // nrep*NCK f32
    unsigned short* sums_bf = (unsigned short*)(counts + (size_t)nrep * NCK); // nrep*NMEANS u16

    hipMemsetAsync(counts, 0, (size_t)nrep * per_rep, stream);

    vq_prep<<<(NCK * 16) / 256, 256, 0, stream>>>(means, q, mbf);

    vq_score<<<NUM_HEADS * 64, 256, 0, stream>>>(x, means, mbf, q, ids_f);  // 512 blocks = 2/CU

    vq_scatter<<<(NIDS * 32) / 256, 256, 0, stream>>>(x, ids_f, counts, sums_bf, nrep - 1);

    vq_final<<<NMEANS / 256, 256, 0, stream>>>(means, counts, sums_bf, out_means, nrep);
}

// Round 17
// 92.384 us; speedup vs baseline: 1.5181x; 1.5181x over previous
//
#include <hip/hip_runtime.h>

#define NUM_HEADS 8
#define DIM 64
#define NCLUST 512
#define NTOK 16384          // 8*2048 tokens
#define ROWLEN 512          // NUM_HEADS*DIM floats per token row
#define NIDS (NTOK * NUM_HEADS)           // 131072
#define NMEANS (NUM_HEADS * NCLUST * DIM) // 262144
#define NCK (NUM_HEADS * NCLUST)          // 4096
#define CAP 8               // candidate slots per token
#define DELTA 0.35f         // ~19 sigma of bf16 coarse-score noise

typedef unsigned long long u64;
typedef short bf16x8 __attribute__((ext_vector_type(8)));
typedef float f32x4 __attribute__((ext_vector_type(4)));

__device__ __forceinline__ unsigned short f2bf(float f) {   // RNE f32->bf16 bits
    unsigned b = __float_as_uint(f);
    return (unsigned short)((b + 0x7fffu + ((b >> 16) & 1u)) >> 16);
}
__device__ __forceinline__ unsigned pack2bf(float lo, float hi) {
    return (unsigned)f2bf(lo) | ((unsigned)f2bf(hi) << 16);
}
__device__ __forceinline__ float bf2f(unsigned short b) {
    return __uint_as_float((unsigned)b << 16);
}
__device__ __forceinline__ u64 packkey(float s, int k) {    // u64 MIN == max s, tie -> min k
    unsigned u = __float_as_uint(s);
    unsigned ord = (u & 0x80000000u) ? ~u : (u | 0x80000000u);
    return ((u64)(~ord) << 32) | (unsigned)k;
}
// swizzled byte offset into a [rows][128B] LDS tile (G4 XOR pattern)
__device__ __forceinline__ int swz(int row, int byte_in_row) {
    return row * 128 + (byte_in_row ^ ((row & 7) << 4));
}

// ---------------- kernel 0: fused prep: q = 0.5*|m|^2 and means f32->bf16 ----
__global__ void vq_prep(const float* __restrict__ means,
                        float* __restrict__ q,
                        unsigned short* __restrict__ mbf) {
    int g = blockIdx.x * blockDim.x + threadIdx.x;   // 0..65535
    int row = g >> 4, c = g & 15;
    float4 v = *(const float4*)(means + (size_t)row * DIM + c * 4);
    ushort4 b;
    b.x = f2bf(v.x); b.y = f2bf(v.y); b.z = f2bf(v.z); b.w = f2bf(v.w);
    *(ushort4*)(mbf + (size_t)row * DIM + c * 4) = b;
    float s = fmaf(v.x, v.x, fmaf(v.y, v.y, fmaf(v.z, v.z, v.w * v.w)));
#pragma unroll
    for (int off = 1; off < 16; off <<= 1) s += __shfl_xor(s, off, 64);
    if (c == 0) q[row] = 0.5f * s;
}

// ---------------- kernel 1: PERSISTENT-MEANS coarse MFMA + candidates + rescore ----
// r16 structure, r16 BUG FIXED: the pass loop is now #pragma unroll so the
// af[][] indices are compile-time constants (rule #20: runtime-indexed
// ext_vector arrays go to scratch -> 123MB spill traffic in r16).
// 512 blocks (2/CU), block = one head; head's full bf16 means (64KB) staged
// ONCE via global_load_lds (pre-swizzled source), ONE barrier, then each wave
// independently: 2 passes x 2 token-tiles, two-sweep final-threshold
// candidates (wave-private LDS lists), exact f32 rescore + CAP fallback.
__global__ __launch_bounds__(256, 2) void vq_score(const float* __restrict__ x,
                                                   const float* __restrict__ means,
                                                   const unsigned short* __restrict__ mbf,
                                                   const float* __restrict__ q,
                                                   float* __restrict__ ids_f) {
    __shared__ __align__(16) unsigned char msq[NCLUST * 128];  // 64 KB all means (swz)
    __shared__ float qs[NCLUST];                               // 2 KB
    __shared__ int cnt[4][32];                                 // wave-private
    __shared__ unsigned short candL[4][32][CAP];               // wave-private

    const int head = blockIdx.x >> 6;        // 64 blocks per head
    const int bloc = blockIdx.x & 63;
    const int tid  = threadIdx.x;
    const int wv = tid >> 6, l = tid & 63;
    const int lg = l >> 4, lc = l & 15;
    const int wg = bloc * 4 + wv;            // 0..255 wave index within head
    const int tile0 = wg * 4;                // this wave's 4 tiles (of 1024)

    // ---- stage ALL 512 means rows (64KB) once; pre-swizzled source ----
    {
        const unsigned char* gbase = (const unsigned char*)mbf
            + (size_t)head * NCLUST * (DIM * 2);
        const int rloc = l >> 3;
        const int srcb = ((l & 7) << 4) ^ (rloc << 4);
#pragma unroll
        for (int i = 0; i < 16; ++i) {
            int chunk = wv * 16 + i;                           // 0..63
            const unsigned char* src = gbase + (chunk * 8 + rloc) * 128 + srcb;
            __builtin_amdgcn_global_load_lds(
                (const __attribute__((address_space(1))) unsigned int*)src,
                (__attribute__((address_space(3))) unsigned int*)(msq + chunk * 1024),
                16, 0, 0);
        }
    }
    qs[tid] = q[head * NCLUST + tid];
    qs[tid + 256] = q[head * NCLUST + tid + 256];

    // ---- A fragments for all 4 tiles upfront (layout validated r5/r12) ----
    bf16x8 af[4][2];
#pragma unroll
    for (int t = 0; t < 4; ++t) {
        const float* xrow = x + (size_t)((tile0 + t) * 16 + lc) * ROWLEN + head * DIM;
#pragma unroll
        for (int ks = 0; ks < 2; ++ks) {
            float av[8];
            *(float4*)&av[0] = *(const float4*)(xrow + ks * 32 + lg * 8);
            *(float4*)&av[4] = *(const float4*)(xrow + ks * 32 + lg * 8 + 4);
#pragma unroll
            for (int j = 0; j < 8; ++j) af[t][ks][j] = (short)f2bf(av[j]);
        }
    }
    __syncthreads();        // the ONLY barrier: msq + qs ready

    // ========== 2 passes x 2 tiles, barrier-free; FULLY UNROLLED (rule #20) ==========
#pragma unroll
    for (int ps = 0; ps < 2; ++ps) {
        if (l < 32) cnt[wv][l] = 0;           // wave-private reset

        float best[2][4];
#pragma unroll
        for (int tt = 0; tt < 2; ++tt)
#pragma unroll
            for (int r = 0; r < 4; ++r) best[tt][r] = -3.0e38f;

        // ---- sweep 1: fold max (b0/b1 shared across the 2 tiles) ----
        for (int ct = 0; ct < 32; ++ct) {
            bf16x8 b0 = *(const bf16x8*)(msq + swz(ct * 16 + lc, 0 + lg * 16));
            bf16x8 b1 = *(const bf16x8*)(msq + swz(ct * 16 + lc, 64 + lg * 16));
            float qv = qs[ct * 16 + lc];
#pragma unroll
            for (int tt = 0; tt < 2; ++tt) {
                f32x4 acc = (f32x4){-qv, -qv, -qv, -qv};   // C-in = -q_k
                acc = __builtin_amdgcn_mfma_f32_16x16x32_bf16(af[ps * 2 + tt][0], b0, acc, 0, 0, 0);
                acc = __builtin_amdgcn_mfma_f32_16x16x32_bf16(af[ps * 2 + tt][1], b1, acc, 0, 0, 0);
#pragma unroll
                for (int r = 0; r < 4; ++r) best[tt][r] = fmaxf(best[tt][r], acc[r]);
            }
        }
        float thr[2][4];
#pragma unroll
        for (int tt = 0; tt < 2; ++tt)
#pragma unroll
            for (int r = 0; r < 4; ++r) {
#pragma unroll
                for (int off = 1; off < 16; off <<= 1)
                    best[tt][r] = fmaxf(best[tt][r], __shfl_xor(best[tt][r], off, 64));
                thr[tt][r] = best[tt][r] - DELTA;
            }

        // ---- sweep 2: recompute + insert (final threshold -> n ~ 1.05) ----
        for (int ct = 0; ct < 32; ++ct) {
            bf16x8 b0 = *(const bf16x8*)(msq + swz(ct * 16 + lc, 0 + lg * 16));
            bf16x8 b1 = *(const bf16x8*)(msq + swz(ct * 16 + lc, 64 + lg * 16));
            float qv = qs[ct * 16 + lc];
            int k = ct * 16 + lc;
#pragma unroll
            for (int tt = 0; tt < 2; ++tt) {
                f32x4 acc = (f32x4){-qv, -qv, -qv, -qv};
                acc = __builtin_amdgcn_mfma_f32_16x16x32_bf16(af[ps * 2 + tt][0], b0, acc, 0, 0, 0);
                acc = __builtin_amdgcn_mfma_f32_16x16x32_bf16(af[ps * 2 + tt][1], b1, acc, 0, 0, 0);
#pragma unroll
                for (int r = 0; r < 4; ++r) {
                    if (acc[r] >= thr[tt][r]) {
                        int tl = tt * 16 + lg * 4 + r;          // 0..31
                        int slot = atomicAdd(&cnt[wv][tl], 1);
                        if (slot < CAP) candL[wv][tl][slot] = (unsigned short)k;
                    }
                }
            }
        }

        // ---- exact f32 rescore (16-lane group per token) + id write ----
        for (int g = 0; g < 8; ++g) {
            int tl = g * 4 + lg;                                // 0..31
            int token = (tile0 + ps * 2 + (tl >> 4)) * 16 + (tl & 15);
            int n = cnt[wv][tl];
            const float4 xv = *(const float4*)(x + (size_t)token * ROWLEN + head * DIM + lc * 4);
            u64 bk = ~0ull;
            if (n > CAP) {      // dropped inserts -> exact full scan (never hot)
                for (int k = 0; k < NCLUST; ++k) {
                    const float4 mv = *(const float4*)(means + ((size_t)head * NCLUST + k) * DIM + lc * 4);
                    float p = fmaf(xv.x, mv.x, fmaf(xv.y, mv.y, fmaf(xv.z, mv.z, xv.w * mv.w)));
#pragma unroll
                    for (int off = 1; off < 16; off <<= 1) p += __shfl_xor(p, off, 64);
                    u64 cd = packkey(p - qs[k], k);
                    bk = cd < bk ? cd : bk;
                }
            } else {
                for (int j = 0; j < n; ++j) {
                    int k = candL[wv][tl][j];
                    const float4 mv = *(const float4*)(means + ((size_t)head * NCLUST + k) * DIM + lc * 4);
                    float p = fmaf(xv.x, mv.x, fmaf(xv.y, mv.y, fmaf(xv.z, mv.z, xv.w * mv.w)));
#pragma unroll
                    for (int off = 1; off < 16; off <<= 1) p += __shfl_xor(p, off, 64);
                    u64 cd = packkey(p - qs[k], k);
                    bk = cd < bk ? cd : bk;
                }
            }
            if (lc == 0) ids_f[(size_t)token * NUM_HEADS + head] = (float)(unsigned)(bk & 0x1ffu);
        }
    }
}

// ---------------- kernel 2: scatter via packed bf16 atomics (r9-validated) ----
__global__ void vq_scatter(const float* __restrict__ x,
                           const float* __restrict__ ids_f,
                           float* __restrict__ counts,
                           unsigned short* __restrict__ sums_bf,
                           int rep_mask) {
    int g = blockIdx.x * blockDim.x + threadIdx.x;
    int p = g >> 5;                      // pair index, 0..131071
    int l32 = threadIdx.x & 31;
    int token = p >> 3;
    int h = p & 7;
    int rep = token & rep_mask;
    int id = (int)ids_f[p];              // broadcast load
    float2 xv = *(const float2*)(x + (size_t)token * ROWLEN + h * DIM + l32 * 2);
    unsigned val = pack2bf(xv.x, xv.y);
    unsigned short* dst = sums_bf + (size_t)rep * NMEANS
                        + (((size_t)h * NCLUST + id) << 6) + l32 * 2;
    asm volatile("global_atomic_pk_add_bf16 %0, %1, off" :: "v"(dst), "v"(val) : "memory");
    if (l32 == 0) atomicAdd(&counts[rep * NCK + h * NCLUST + id], 1.0f);
}

// ---------------- kernel 3: EMA finalize (sums replicas, bf16) ----------------
__global__ void vq_final(const float* __restrict__ means,
                         const float* __restrict__ counts,
                         const unsigned short* __restrict__ sums_bf,
                         float* __restrict__ out_means,
                         int nrep) {
    int i = blockIdx.x * blockDim.x + threadIdx.x;   // 0..262143
    int ck = i >> 6;
    float c = 0.f, s = 0.f;
    for (int r = 0; r < nrep; ++r) {
        c += counts[r * NCK + ck];
        s += bf2f(sums_bf[(size_t)r * NMEANS + i]);
    }
    float nm = s / (1e-6f + c);
    out_means[i] = 0.999f * means[i] + 0.001f * nm;
}

extern "C" void kernel_launch(void* const* d_in, const int* in_sizes, int n_in,
                              void* d_out, int out_size, void* d_ws, size_t ws_size,
                              hipStream_t stream) {
    const float* x     = (const float*)d_in[0];   // [8,2048,512]
    const float* means = (const float*)d_in[1];   // [8,512,64]

    float* out       = (float*)d_out;
    float* ids_f     = out;            // 131072 floats (cluster ids as float)
    float* out_means = out + NIDS;     // 262144 floats

    // ---- workspace layout ----
    float*          q   = (float*)d_ws;                 // NCK f32 (16 KB)
    unsigned short* mbf = (unsigned short*)(q + NCK);   // NMEANS u16 (512 KB)
    float*          fbase = (float*)(mbf + NMEANS);
    size_t core = (size_t)((char*)fbase - (char*)d_ws);

    size_t per_rep = (size_t)NCK * sizeof(float) + (size_t)NMEANS * sizeof(unsigned short);
    int nrep = 1;
    for (int r = 8; r > 1; r >>= 1) {
        if (ws_size >= core + (size_t)r * per_rep) { nrep = r; break; }
    }
    float*          counts  = fbase;                                   // nrep*NCK f32
    unsigned short* sums_bf = (unsigned short*)(counts + (size_t)nrep * NCK); // nrep*NMEANS u16

    hipMemsetAsync(counts, 0, (size_t)nrep * per_rep, stream);

    vq_prep<<<(NCK * 16) / 256, 256, 0, stream>>>(means, q, mbf);

    vq_score<<<NUM_HEADS * 64, 256, 0, stream>>>(x, means, mbf, q, ids_f);  // 512 blocks = 2/CU

    vq_scatter<<<(NIDS * 32) / 256, 256, 0, stream>>>(x, ids_f, counts, sums_bf, nrep - 1);

    vq_final<<<NMEANS / 256, 256, 0, stream>>>(means, counts, sums_bf, out_means, nrep);
}

// Round 18
// 80.986 us; speedup vs baseline: 1.7318x; 1.1407x over previous
//
#include <hip/hip_runtime.h>

#define NUM_HEADS 8
#define DIM 64
#define NCLUST 512
#define NTOK 16384          // 8*2048 tokens
#define ROWLEN 512          // NUM_HEADS*DIM floats per token row
#define NIDS (NTOK * NUM_HEADS)           // 131072
#define NMEANS (NUM_HEADS * NCLUST * DIM) // 262144
#define NCK (NUM_HEADS * NCLUST)          // 4096
#define TPB 64              // tokens per block (1 token-tile per wave)
#define KQ 128              // clusters per staged quarter
#define CAP 8               // candidate slots per token
#define DELTA 0.35f         // ~19 sigma of bf16 coarse-score noise

typedef unsigned long long u64;
typedef short bf16x8 __attribute__((ext_vector_type(8)));
typedef float f32x4 __attribute__((ext_vector_type(4)));

__device__ __forceinline__ unsigned short f2bf(float f) {   // RNE f32->bf16 bits
    unsigned b = __float_as_uint(f);
    return (unsigned short)((b + 0x7fffu + ((b >> 16) & 1u)) >> 16);
}
__device__ __forceinline__ unsigned pack2bf(float lo, float hi) {
    return (unsigned)f2bf(lo) | ((unsigned)f2bf(hi) << 16);
}
__device__ __forceinline__ float bf2f(unsigned short b) {
    return __uint_as_float((unsigned)b << 16);
}
__device__ __forceinline__ u64 packkey(float s, int k) {    // u64 MIN == max s, tie -> min k
    unsigned u = __float_as_uint(s);
    unsigned ord = (u & 0x80000000u) ? ~u : (u | 0x80000000u);
    return ((u64)(~ord) << 32) | (unsigned)k;
}
// swizzled byte offset into a [rows][128B] LDS tile (G4 XOR pattern)
__device__ __forceinline__ int swz(int row, int byte_in_row) {
    return row * 128 + (byte_in_row ^ ((row & 7) << 4));
}

// ---------------- kernel 0: fused prep: q = 0.5*|m|^2 and means f32->bf16 ----
__global__ void vq_prep(const float* __restrict__ means,
                        float* __restrict__ q,
                        unsigned short* __restrict__ mbf) {
    int g = blockIdx.x * blockDim.x + threadIdx.x;   // 0..65535
    int row = g >> 4, c = g & 15;
    float4 v = *(const float4*)(means + (size_t)row * DIM + c * 4);
    ushort4 b;
    b.x = f2bf(v.x); b.y = f2bf(v.y); b.z = f2bf(v.z); b.w = f2bf(v.w);
    *(ushort4*)(mbf + (size_t)row * DIM + c * 4) = b;
    float s = fmaf(v.x, v.x, fmaf(v.y, v.y, fmaf(v.z, v.z, v.w * v.w)));
#pragma unroll
    for (int off = 1; off < 16; off <<= 1) s += __shfl_xor(s, off, 64);
    if (c == 0) q[row] = 0.5f * s;
}

// ---------------- kernel 1: coarse MFMA + candidates + exact rescore ----------
// CHAMPION CONFIG (round 12, 75.5us total): TPB=64, A-frags direct from global,
// msq staged via global_load_lds (linear dest + inverse-swizzled source, rule
// #21). Two-sweep exact-candidate scheme, quarter staging, reverse sweep-2
// reusing quarter 3. No prefetch registers -> no spill at high occupancy.
__global__ __launch_bounds__(256, 4) void vq_score(const float* __restrict__ x,
                                                   const float* __restrict__ means,
                                                   const unsigned short* __restrict__ mbf,
                                                   const float* __restrict__ q,
                                                   float* __restrict__ ids_f) {
    __shared__ __align__(16) unsigned char msq[KQ * 128];    // 16 KB means quarter (swz)
    __shared__ float qs[NCLUST];                             // 2 KB
    __shared__ int cnt[TPB];                                 // 0.25 KB
    __shared__ unsigned short candL[TPB][CAP];               // 1 KB

    const int head = blockIdx.y;
    const int t0   = blockIdx.x * TPB;
    const int tid  = threadIdx.x;
    const int wv = tid >> 6, l = tid & 63;
    const int lg = l >> 4, lc = l & 15;
    const int twave = wv * 16;

    // ---- async stage of one 128-cluster quarter via global_load_lds ----
    // LDS linear: lane l of chunk c owns bytes c*1024 + l*16 -> row = c*8 + (l>>3),
    // b' = (l&7)*16. Content must be mbf[row][b' ^ ((row&7)<<4)] (involution).
    auto stage_async = [&](int qt) {
        const unsigned char* gbase = (const unsigned char*)mbf
            + ((size_t)head * NCLUST + (size_t)qt * KQ) * (DIM * 2);
        const int rloc = l >> 3;                               // 0..7
        const int srcb = ((l & 7) << 4) ^ (rloc << 4);         // swizzled byte in row
#pragma unroll
        for (int i = 0; i < 4; ++i) {
            int chunk = wv * 4 + i;                            // 0..15
            const unsigned char* src = gbase + (chunk * 8 + rloc) * 128 + srcb;
            __builtin_amdgcn_global_load_lds(
                (const __attribute__((address_space(1))) unsigned int*)src,
                (__attribute__((address_space(3))) unsigned int*)(msq + chunk * 1024),
                16, 0, 0);
        }
    };

    // ---- A fragments DIRECT from global: lane l = token twave+lc, dims ks*32+lg*8 ----
    bf16x8 af[2];
    {
        const float* xrow = x + (size_t)(t0 + twave + lc) * ROWLEN + head * DIM;
#pragma unroll
        for (int ks = 0; ks < 2; ++ks) {
            float av[8];
            *(float4*)&av[0] = *(const float4*)(xrow + ks * 32 + lg * 8);
            *(float4*)&av[4] = *(const float4*)(xrow + ks * 32 + lg * 8 + 4);
#pragma unroll
            for (int j = 0; j < 8; ++j) af[ks][j] = (short)f2bf(av[j]);
        }
    }
    // ---- stage q, zero cnt, stage quarter 0 ----
    qs[tid] = q[head * NCLUST + tid];
    qs[tid + 256] = q[head * NCLUST + tid + 256];
    if (tid < TPB) cnt[tid] = 0;
    stage_async(0);
    __syncthreads();        // drains vmcnt: msq(q0) ready; qs/cnt visible

    float best[4];
#pragma unroll
    for (int r = 0; r < 4; ++r) best[r] = -3.0e38f;
    float thr[4];

    auto sweep1_q = [&](int qt) {
#pragma unroll
        for (int ct = 0; ct < KQ / 16; ++ct) {
            bf16x8 b0 = *(const bf16x8*)(msq + swz(ct * 16 + lc, 0 + lg * 16));
            bf16x8 b1 = *(const bf16x8*)(msq + swz(ct * 16 + lc, 64 + lg * 16));
            float qv = qs[qt * KQ + ct * 16 + lc];
            f32x4 acc = (f32x4){-qv, -qv, -qv, -qv};   // C-in = -q_k: acc out == score
            acc = __builtin_amdgcn_mfma_f32_16x16x32_bf16(af[0], b0, acc, 0, 0, 0);
            acc = __builtin_amdgcn_mfma_f32_16x16x32_bf16(af[1], b1, acc, 0, 0, 0);
#pragma unroll
            for (int r = 0; r < 4; ++r) best[r] = fmaxf(best[r], acc[r]);
        }
    };
    auto collect_q = [&](int qt) {
#pragma unroll
        for (int ct = 0; ct < KQ / 16; ++ct) {
            bf16x8 b0 = *(const bf16x8*)(msq + swz(ct * 16 + lc, 0 + lg * 16));
            bf16x8 b1 = *(const bf16x8*)(msq + swz(ct * 16 + lc, 64 + lg * 16));
            float qv = qs[qt * KQ + ct * 16 + lc];
            int k = qt * KQ + ct * 16 + lc;
            f32x4 acc = (f32x4){-qv, -qv, -qv, -qv};
            acc = __builtin_amdgcn_mfma_f32_16x16x32_bf16(af[0], b0, acc, 0, 0, 0);
            acc = __builtin_amdgcn_mfma_f32_16x16x32_bf16(af[1], b1, acc, 0, 0, 0);
#pragma unroll
            for (int r = 0; r < 4; ++r) {
                if (acc[r] >= thr[r]) {
                    int tok = twave + lg * 4 + r;
                    int slot = atomicAdd(&cnt[tok], 1);
                    if (slot < CAP) candL[tok][slot] = (unsigned short)k;
                }
            }
        }
    };

    // ================= sweep 1 (quarters 0..3) =================
    for (int qt = 0; qt < 4; ++qt) {
        sweep1_q(qt);
        if (qt < 3) {
            __syncthreads();            // readers done with msq
            stage_async(qt + 1);
            __syncthreads();            // stage drained (compiler waits vmcnt)
        }
    }
    // butterfly across the 16 cluster-lanes; all lanes converge to token max
#pragma unroll
    for (int r = 0; r < 4; ++r) {
#pragma unroll
        for (int off = 1; off < 16; off <<= 1)
            best[r] = fmaxf(best[r], __shfl_xor(best[r], off, 64));
        thr[r] = best[r] - DELTA;
    }

    // ================= sweep 2 (reverse order: q3 already staged) ============
    collect_q(3);                       // msq still holds quarter 3
    for (int qt = 2; qt >= 0; --qt) {
        __syncthreads();
        stage_async(qt);
        __syncthreads();
        collect_q(qt);
    }
    __syncthreads();                    // cnt/candL complete

    // ================= exact f32 rescore of candidates =================
    // 16-lane subgroup per token (lane lc = dims 4lc..4lc+3).
#pragma unroll
    for (int g = 0; g < 4; ++g) {
        int tok = twave + g * 4 + lg;
        int n = cnt[tok]; n = n < CAP ? n : CAP;
        const float4 xv = *(const float4*)(x + (size_t)(t0 + tok) * ROWLEN + head * DIM + lc * 4);
        u64 bk = ~0ull;
        for (int j = 0; j < n; ++j) {
            int k = candL[tok][j];
            const float4 mv = *(const float4*)(means + ((size_t)head * NCLUST + k) * DIM + lc * 4);
            float p = fmaf(xv.x, mv.x, fmaf(xv.y, mv.y, fmaf(xv.z, mv.z, xv.w * mv.w)));
#pragma unroll
            for (int off = 1; off < 16; off <<= 1) p += __shfl_xor(p, off, 64);
            u64 cd = packkey(p - qs[k], k);
            bk = cd < bk ? cd : bk;
        }
        if (lc == 0) ids_f[(size_t)(t0 + tok) * NUM_HEADS + head] = (float)(unsigned)(bk & 0x1ffu);
    }
}

// ---------------- kernel 2: scatter via packed bf16 atomics (r9-validated) ----
__global__ void vq_scatter(const float* __restrict__ x,
                           const float* __restrict__ ids_f,
                           float* __restrict__ counts,
                           unsigned short* __restrict__ sums_bf,
                           int rep_mask) {
    int g = blockIdx.x * blockDim.x + threadIdx.x;
    int p = g >> 5;                      // pair index, 0..131071
    int l32 = threadIdx.x & 31;
    int token = p >> 3;
    int h = p & 7;
    int rep = token & rep_mask;
    int id = (int)ids_f[p];              // broadcast load
    float2 xv = *(const float2*)(x + (size_t)token * ROWLEN + h * DIM + l32 * 2);
    unsigned val = pack2bf(xv.x, xv.y);
    unsigned short* dst = sums_bf + (size_t)rep * NMEANS
                        + (((size_t)h * NCLUST + id) << 6) + l32 * 2;
    asm volatile("global_atomic_pk_add_bf16 %0, %1, off" :: "v"(dst), "v"(val) : "memory");
    if (l32 == 0) atomicAdd(&counts[rep * NCK + h * NCLUST + id], 1.0f);
}

// ---------------- kernel 3: EMA finalize (sums replicas, bf16) ----------------
__global__ void vq_final(const float* __restrict__ means,
                         const float* __restrict__ counts,
                         const unsigned short* __restrict__ sums_bf,
                         float* __restrict__ out_means,
                         int nrep) {
    int i = blockIdx.x * blockDim.x + threadIdx.x;   // 0..262143
    int ck = i >> 6;
    float c = 0.f, s = 0.f;
    for (int r = 0; r < nrep; ++r) {
        c += counts[r * NCK + ck];
        s += bf2f(sums_bf[(size_t)r * NMEANS + i]);
    }
    float nm = s / (1e-6f + c);
    out_means[i] = 0.999f * means[i] + 0.001f * nm;
}

extern "C" void kernel_launch(void* const* d_in, const int* in_sizes, int n_in,
                              void* d_out, int out_size, void* d_ws, size_t ws_size,
                              hipStream_t stream) {
    const float* x     = (const float*)d_in[0];   // [8,2048,512]
    const float* means = (const float*)d_in[1];   // [8,512,64]

    float* out       = (float*)d_out;
    float* ids_f     = out;            // 131072 floats (cluster ids as float)
    float* out_means = out + NIDS;     // 262144 floats

    // ---- workspace layout ----
    float*          q   = (float*)d_ws;                 // NCK f32 (16 KB)
    unsigned short* mbf = (unsigned short*)(q + NCK);   // NMEANS u16 (512 KB)
    float*          fbase = (float*)(mbf + NMEANS);
    size_t core = (size_t)((char*)fbase - (char*)d_ws);

    size_t per_rep = (size_t)NCK * sizeof(float) + (size_t)NMEANS * sizeof(unsigned short);
    int nrep = 1;
    for (int r = 8; r > 1; r >>= 1) {
        if (ws_size >= core + (size_t)r * per_rep) { nrep = r; break; }
    }
    float*          counts  = fbase;                                   // nrep*NCK f32
    unsigned short* sums_bf = (unsigned short*)(counts + (size_t)nrep * NCK); // nrep*NMEANS u16

    hipMemsetAsync(counts, 0, (size_t)nrep * per_rep, stream);

    vq_prep<<<(NCK * 16) / 256, 256, 0, stream>>>(means, q, mbf);

    dim3 gs(NTOK / TPB, NUM_HEADS);   // (256, 8) = 2048 blocks = 8/CU exactly
    vq_score<<<gs, 256, 0, stream>>>(x, means, mbf, q, ids_f);

    vq_scatter<<<(NIDS * 32) / 256, 256, 0, stream>>>(x, ids_f, counts, sums_bf, nrep - 1);

    vq_final<<<NMEANS / 256, 256, 0, stream>>>(means, counts, sums_bf, out_means, nrep);
}

// Round 19
// 73.853 us; speedup vs baseline: 1.8990x; 1.0966x over previous
//
#include <hip/hip_runtime.h>

#define NUM_HEADS 8
#define DIM 64
#define NCLUST 512
#define NTOK 16384          // 8*2048 tokens
#define ROWLEN 512          // NUM_HEADS*DIM floats per token row
#define NIDS (NTOK * NUM_HEADS)           // 131072
#define NMEANS (NUM_HEADS * NCLUST * DIM) // 262144
#define NCK (NUM_HEADS * NCLUST)          // 4096
#define TPB 64              // tokens per block (1 token-tile per wave)
#define KQ 128              // clusters per staged quarter
#define CAP 8               // candidate slots per token
#define DELTA 0.35f         // ~19 sigma of bf16 coarse-score noise

typedef unsigned long long u64;
typedef short bf16x8 __attribute__((ext_vector_type(8)));
typedef float f32x4 __attribute__((ext_vector_type(4)));

__device__ __forceinline__ unsigned short f2bf(float f) {   // RNE f32->bf16 bits
    unsigned b = __float_as_uint(f);
    return (unsigned short)((b + 0x7fffu + ((b >> 16) & 1u)) >> 16);
}
__device__ __forceinline__ unsigned pack2bf(float lo, float hi) {
    return (unsigned)f2bf(lo) | ((unsigned)f2bf(hi) << 16);
}
__device__ __forceinline__ float bf2f(unsigned short b) {
    return __uint_as_float((unsigned)b << 16);
}
__device__ __forceinline__ u64 packkey(float s, int k) {    // u64 MIN == max s, tie -> min k
    unsigned u = __float_as_uint(s);
    unsigned ord = (u & 0x80000000u) ? ~u : (u | 0x80000000u);
    return ((u64)(~ord) << 32) | (unsigned)k;
}
// swizzled byte offset into a [rows][128B] LDS tile (G4 XOR pattern)
__device__ __forceinline__ int swz(int row, int byte_in_row) {
    return row * 128 + (byte_in_row ^ ((row & 7) << 4));
}

// ---------------- kernel 0: fused prep: q = 0.5*|m|^2 and means f32->bf16 ----
__global__ void vq_prep(const float* __restrict__ means,
                        float* __restrict__ q,
                        unsigned short* __restrict__ mbf) {
    int g = blockIdx.x * blockDim.x + threadIdx.x;   // 0..65535
    int row = g >> 4, c = g & 15;
    float4 v = *(const float4*)(means + (size_t)row * DIM + c * 4);
    ushort4 b;
    b.x = f2bf(v.x); b.y = f2bf(v.y); b.z = f2bf(v.z); b.w = f2bf(v.w);
    *(ushort4*)(mbf + (size_t)row * DIM + c * 4) = b;
    float s = fmaf(v.x, v.x, fmaf(v.y, v.y, fmaf(v.z, v.z, v.w * v.w)));
#pragma unroll
    for (int off = 1; off < 16; off <<= 1) s += __shfl_xor(s, off, 64);
    if (c == 0) q[row] = 0.5f * s;
}

// ---------------- kernel 1: coarse MFMA + candidates + exact rescore ----------
// CHAMPION CONFIG (round 12, 75.5us total): TPB=64, A-frags direct from global,
// msq staged via global_load_lds (linear dest + inverse-swizzled source, rule
// #21). Two-sweep exact-candidate scheme, quarter staging, reverse sweep-2
// reusing quarter 3. __launch_bounds__(256, 8) is ESSENTIAL (r18 regression:
// (256,4) -> VGPR 40/occ 48%/62us; (256,8) -> VGPR 32/occ 75%/51us).
__global__ __launch_bounds__(256, 8) void vq_score(const float* __restrict__ x,
                                                   const float* __restrict__ means,
                                                   const unsigned short* __restrict__ mbf,
                                                   const float* __restrict__ q,
                                                   float* __restrict__ ids_f) {
    __shared__ __align__(16) unsigned char msq[KQ * 128];    // 16 KB means quarter (swz)
    __shared__ float qs[NCLUST];                             // 2 KB
    __shared__ int cnt[TPB];                                 // 0.25 KB
    __shared__ unsigned short candL[TPB][CAP];               // 1 KB

    const int head = blockIdx.y;
    const int t0   = blockIdx.x * TPB;
    const int tid  = threadIdx.x;
    const int wv = tid >> 6, l = tid & 63;
    const int lg = l >> 4, lc = l & 15;
    const int twave = wv * 16;

    // ---- async stage of one 128-cluster quarter via global_load_lds ----
    // LDS linear: lane l of chunk c owns bytes c*1024 + l*16 -> row = c*8 + (l>>3),
    // b' = (l&7)*16. Content must be mbf[row][b' ^ ((row&7)<<4)] (involution).
    auto stage_async = [&](int qt) {
        const unsigned char* gbase = (const unsigned char*)mbf
            + ((size_t)head * NCLUST + (size_t)qt * KQ) * (DIM * 2);
        const int rloc = l >> 3;                               // 0..7
        const int srcb = ((l & 7) << 4) ^ (rloc << 4);         // swizzled byte in row
#pragma unroll
        for (int i = 0; i < 4; ++i) {
            int chunk = wv * 4 + i;                            // 0..15
            const unsigned char* src = gbase + (chunk * 8 + rloc) * 128 + srcb;
            __builtin_amdgcn_global_load_lds(
                (const __attribute__((address_space(1))) unsigned int*)src,
                (__attribute__((address_space(3))) unsigned int*)(msq + chunk * 1024),
                16, 0, 0);
        }
    };

    // ---- A fragments DIRECT from global: lane l = token twave+lc, dims ks*32+lg*8 ----
    bf16x8 af[2];
    {
        const float* xrow = x + (size_t)(t0 + twave + lc) * ROWLEN + head * DIM;
#pragma unroll
        for (int ks = 0; ks < 2; ++ks) {
            float av[8];
            *(float4*)&av[0] = *(const float4*)(xrow + ks * 32 + lg * 8);
            *(float4*)&av[4] = *(const float4*)(xrow + ks * 32 + lg * 8 + 4);
#pragma unroll
            for (int j = 0; j < 8; ++j) af[ks][j] = (short)f2bf(av[j]);
        }
    }
    // ---- stage q, zero cnt, stage quarter 0 ----
    qs[tid] = q[head * NCLUST + tid];
    qs[tid + 256] = q[head * NCLUST + tid + 256];
    if (tid < TPB) cnt[tid] = 0;
    stage_async(0);
    __syncthreads();        // drains vmcnt: msq(q0) ready; qs/cnt visible

    float best[4];
#pragma unroll
    for (int r = 0; r < 4; ++r) best[r] = -3.0e38f;
    float thr[4];

    auto sweep1_q = [&](int qt) {
#pragma unroll
        for (int ct = 0; ct < KQ / 16; ++ct) {
            bf16x8 b0 = *(const bf16x8*)(msq + swz(ct * 16 + lc, 0 + lg * 16));
            bf16x8 b1 = *(const bf16x8*)(msq + swz(ct * 16 + lc, 64 + lg * 16));
            float qv = qs[qt * KQ + ct * 16 + lc];
            f32x4 acc = (f32x4){-qv, -qv, -qv, -qv};   // C-in = -q_k: acc out == score
            acc = __builtin_amdgcn_mfma_f32_16x16x32_bf16(af[0], b0, acc, 0, 0, 0);
            acc = __builtin_amdgcn_mfma_f32_16x16x32_bf16(af[1], b1, acc, 0, 0, 0);
#pragma unroll
            for (int r = 0; r < 4; ++r) best[r] = fmaxf(best[r], acc[r]);
        }
    };
    auto collect_q = [&](int qt) {
#pragma unroll
        for (int ct = 0; ct < KQ / 16; ++ct) {
            bf16x8 b0 = *(const bf16x8*)(msq + swz(ct * 16 + lc, 0 + lg * 16));
            bf16x8 b1 = *(const bf16x8*)(msq + swz(ct * 16 + lc, 64 + lg * 16));
            float qv = qs[qt * KQ + ct * 16 + lc];
            int k = qt * KQ + ct * 16 + lc;
            f32x4 acc = (f32x4){-qv, -qv, -qv, -qv};
            acc = __builtin_amdgcn_mfma_f32_16x16x32_bf16(af[0], b0, acc, 0, 0, 0);
            acc = __builtin_amdgcn_mfma_f32_16x16x32_bf16(af[1], b1, acc, 0, 0, 0);
#pragma unroll
            for (int r = 0; r < 4; ++r) {
                if (acc[r] >= thr[r]) {
                    int tok = twave + lg * 4 + r;
                    int slot = atomicAdd(&cnt[tok], 1);
                    if (slot < CAP) candL[tok][slot] = (unsigned short)k;
                }
            }
        }
    };

    // ================= sweep 1 (quarters 0..3) =================
    for (int qt = 0; qt < 4; ++qt) {
        sweep1_q(qt);
        if (qt < 3) {
            __syncthreads();            // readers done with msq
            stage_async(qt + 1);
            __syncthreads();            // stage drained (compiler waits vmcnt)
        }
    }
    // butterfly across the 16 cluster-lanes; all lanes converge to token max
#pragma unroll
    for (int r = 0; r < 4; ++r) {
#pragma unroll
        for (int off = 1; off < 16; off <<= 1)
            best[r] = fmaxf(best[r], __shfl_xor(best[r], off, 64));
        thr[r] = best[r] - DELTA;
    }

    // ================= sweep 2 (reverse order: q3 already staged) ============
    collect_q(3);                       // msq still holds quarter 3
    for (int qt = 2; qt >= 0; --qt) {
        __syncthreads();
        stage_async(qt);
        __syncthreads();
        collect_q(qt);
    }
    __syncthreads();                    // cnt/candL complete

    // ================= exact f32 rescore of candidates =================
    // 16-lane subgroup per token (lane lc = dims 4lc..4lc+3).
#pragma unroll
    for (int g = 0; g < 4; ++g) {
        int tok = twave + g * 4 + lg;
        int n = cnt[tok]; n = n < CAP ? n : CAP;
        const float4 xv = *(const float4*)(x + (size_t)(t0 + tok) * ROWLEN + head * DIM + lc * 4);
        u64 bk = ~0ull;
        for (int j = 0; j < n; ++j) {
            int k = candL[tok][j];
            const float4 mv = *(const float4*)(means + ((size_t)head * NCLUST + k) * DIM + lc * 4);
            float p = fmaf(xv.x, mv.x, fmaf(xv.y, mv.y, fmaf(xv.z, mv.z, xv.w * mv.w)));
#pragma unroll
            for (int off = 1; off < 16; off <<= 1) p += __shfl_xor(p, off, 64);
            u64 cd = packkey(p - qs[k], k);
            bk = cd < bk ? cd : bk;
        }
        if (lc == 0) ids_f[(size_t)(t0 + tok) * NUM_HEADS + head] = (float)(unsigned)(bk & 0x1ffu);
    }
}

// ---------------- kernel 2: scatter via packed bf16 atomics (r9-validated) ----
__global__ void vq_scatter(const float* __restrict__ x,
                           const float* __restrict__ ids_f,
                           float* __restrict__ counts,
                           unsigned short* __restrict__ sums_bf,
                           int rep_mask) {
    int g = blockIdx.x * blockDim.x + threadIdx.x;
    int p = g >> 5;                      // pair index, 0..131071
    int l32 = threadIdx.x & 31;
    int token = p >> 3;
    int h = p & 7;
    int rep = token & rep_mask;
    int id = (int)ids_f[p];              // broadcast load
    float2 xv = *(const float2*)(x + (size_t)token * ROWLEN + h * DIM + l32 * 2);
    unsigned val = pack2bf(xv.x, xv.y);
    unsigned short* dst = sums_bf + (size_t)rep * NMEANS
                        + (((size_t)h * NCLUST + id) << 6) + l32 * 2;
    asm volatile("global_atomic_pk_add_bf16 %0, %1, off" :: "v"(dst), "v"(val) : "memory");
    if (l32 == 0) atomicAdd(&counts[rep * NCK + h * NCLUST + id], 1.0f);
}

// ---------------- kernel 3: EMA finalize (sums replicas, bf16) ----------------
__global__ void vq_final(const float* __restrict__ means,
                         const float* __restrict__ counts,
                         const unsigned short* __restrict__ sums_bf,
                         float* __restrict__ out_means,
                         int nrep) {
    int i = blockIdx.x * blockDim.x + threadIdx.x;   // 0..262143
    int ck = i >> 6;
    float c = 0.f, s = 0.f;
    for (int r = 0; r < nrep; ++r) {
        c += counts[r * NCK + ck];
        s += bf2f(sums_bf[(size_t)r * NMEANS + i]);
    }
    float nm = s / (1e-6f + c);
    out_means[i] = 0.999f * means[i] + 0.001f * nm;
}

extern "C" void kernel_launch(void* const* d_in, const int* in_sizes, int n_in,
                              void* d_out, int out_size, void* d_ws, size_t ws_size,
                              hipStream_t stream) {
    const float* x     = (const float*)d_in[0];   // [8,2048,512]
    const float* means = (const float*)d_in[1];   // [8,512,64]

    float* out       = (float*)d_out;
    float* ids_f     = out;            // 131072 floats (cluster ids as float)
    float* out_means = out + NIDS;     // 262144 floats

    // ---- workspace layout ----
    float*          q   = (float*)d_ws;                 // NCK f32 (16 KB)
    unsigned short* mbf = (unsigned short*)(q + NCK);   // NMEANS u16 (512 KB)
    float*          fbase = (float*)(mbf + NMEANS);
    size_t core = (size_t)((char*)fbase - (char*)d_ws);

    size_t per_rep = (size_t)NCK * sizeof(float) + (size_t)NMEANS * sizeof(unsigned short);
    int nrep = 1;
    for (int r = 8; r > 1; r >>= 1) {
        if (ws_size >= core + (size_t)r * per_rep) { nrep = r; break; }
    }
    float*          counts  = fbase;                                   // nrep*NCK f32
    unsigned short* sums_bf = (unsigned short*)(counts + (size_t)nrep * NCK); // nrep*NMEANS u16

    hipMemsetAsync(counts, 0, (size_t)nrep * per_rep, stream);

    vq_prep<<<(NCK * 16) / 256, 256, 0, stream>>>(means, q, mbf);

    dim3 gs(NTOK / TPB, NUM_HEADS);   // (256, 8) = 2048 blocks = 8/CU exactly
    vq_score<<<gs, 256, 0, stream>>>(x, means, mbf, q, ids_f);

    vq_scatter<<<(NIDS * 32) / 256, 256, 0, stream>>>(x, ids_f, counts, sums_bf, nrep - 1);

    vq_final<<<NMEANS / 256, 256, 0, stream>>>(means, counts, sums_bf, out_means, nrep);
}